// Round 1
// baseline (6873.661 us; speedup 1.0000x reference)
//
#include <hip/hip_runtime.h>
#include <hip/hip_bf16.h>
#include <math.h>

namespace {
constexpr int V = 32000, D = 1024, L = 8, H = 16, T = 128, F = 2816, DH = 64;
constexpr float EPS = 1e-5f;
constexpr float SCALE = 0.125f; // 1/sqrt(DH)
}

// ---------------- RoPE tables: cos/sin [T, 32] ----------------
__global__ void rope_init_kernel(float* __restrict__ cosT, float* __restrict__ sinT) {
    int t = blockIdx.x;
    int i = threadIdx.x; // 0..31
    float inv = powf(10000.0f, -(2.0f * (float)i) / (float)DH);
    float ang = (float)t * inv;
    cosT[t * 32 + i] = cosf(ang);
    sinT[t * 32 + i] = sinf(ang);
}

// ---------------- Embedding gather: X[t,:] = emb[ids[t],:] ----------------
__global__ void embed_kernel(const int* __restrict__ ids, const float* __restrict__ emb,
                             float* __restrict__ X) {
    int t = blockIdx.x;
    int id = ids[t];
    float4 v = ((const float4*)(emb + (size_t)id * D))[threadIdx.x];
    ((float4*)(X + (size_t)t * D))[threadIdx.x] = v;
}

// ---------------- RMSNorm per row: Y[t,:] = X[t,:] * rsqrt(mean(X^2)+eps) * w ----------------
__global__ void rmsnorm_kernel(const float* __restrict__ X, const float* __restrict__ w,
                               float* __restrict__ Y) {
    int t = blockIdx.x;
    int tid = threadIdx.x; // 256 threads, 4 floats each
    float4 xv = ((const float4*)(X + (size_t)t * D))[tid];
    float s = xv.x * xv.x + xv.y * xv.y + xv.z * xv.z + xv.w * xv.w;
    for (int o = 32; o >= 1; o >>= 1) s += __shfl_xor(s, o);
    __shared__ float red[4];
    if ((tid & 63) == 0) red[tid >> 6] = s;
    __syncthreads();
    float tot = red[0] + red[1] + red[2] + red[3];
    float r = rsqrtf(tot / (float)D + EPS);
    float4 wv = ((const float4*)w)[tid];
    float4 y;
    y.x = xv.x * r * wv.x; y.y = xv.y * r * wv.y;
    y.z = xv.z * r * wv.z; y.w = xv.w * r * wv.w;
    ((float4*)(Y + (size_t)t * D))[tid] = y;
}

// ---------------- fp32 tiled GEMM: C[M,N] = A[M,K] @ B[K,N] (+ Cin) ----------------
// 32x32 tile, block 16x16, 2x2 outputs/thread. M,N,K all multiples of 32.
__global__ void gemm_f32(const float* __restrict__ A, const float* __restrict__ B,
                         const float* __restrict__ Cin, float* __restrict__ C,
                         int N, int K) {
    __shared__ float As[32][33];
    __shared__ float Bs[32][33];
    int tx = threadIdx.x, ty = threadIdx.y;
    int bx = blockIdx.x * 32;
    int by = blockIdx.y * 32;
    int tid = ty * 16 + tx;
    float acc00 = 0.f, acc01 = 0.f, acc10 = 0.f, acc11 = 0.f;
    for (int k0 = 0; k0 < K; k0 += 32) {
        #pragma unroll
        for (int i = tid; i < 32 * 32; i += 256) {
            int r = i >> 5, c = i & 31;
            As[r][c] = A[(size_t)(by + r) * K + (k0 + c)];
            Bs[r][c] = B[(size_t)(k0 + r) * N + (bx + c)];
        }
        __syncthreads();
        #pragma unroll
        for (int kk = 0; kk < 32; ++kk) {
            float a0 = As[ty * 2][kk], a1 = As[ty * 2 + 1][kk];
            float b0 = Bs[kk][tx * 2], b1 = Bs[kk][tx * 2 + 1];
            acc00 = fmaf(a0, b0, acc00);
            acc01 = fmaf(a0, b1, acc01);
            acc10 = fmaf(a1, b0, acc10);
            acc11 = fmaf(a1, b1, acc11);
        }
        __syncthreads();
    }
    int r0 = by + ty * 2, c0 = bx + tx * 2;
    float v00 = acc00, v01 = acc01, v10 = acc10, v11 = acc11;
    if (Cin) {
        v00 += Cin[(size_t)r0 * N + c0];
        v01 += Cin[(size_t)r0 * N + c0 + 1];
        v10 += Cin[(size_t)(r0 + 1) * N + c0];
        v11 += Cin[(size_t)(r0 + 1) * N + c0 + 1];
    }
    C[(size_t)r0 * N + c0] = v00;
    C[(size_t)r0 * N + c0 + 1] = v01;
    C[(size_t)(r0 + 1) * N + c0] = v10;
    C[(size_t)(r0 + 1) * N + c0 + 1] = v11;
}

// ---------------- RoPE apply (in-place on Q and K, layout [T, H, DH]) ----------------
__global__ void rope_apply_kernel(float* __restrict__ Q, float* __restrict__ Kk,
                                  const float* __restrict__ cosT, const float* __restrict__ sinT) {
    int idx = blockIdx.x * 256 + threadIdx.x; // T*H*32 = 65536
    int i = idx & 31;
    int h = (idx >> 5) & (H - 1);
    int t = idx >> 9;
    float c = cosT[t * 32 + i], s = sinT[t * 32 + i];
    size_t base = (size_t)t * D + h * DH;
    float q0 = Q[base + i], q1 = Q[base + i + 32];
    Q[base + i]      = q0 * c - q1 * s;
    Q[base + i + 32] = q1 * c + q0 * s;
    float k0 = Kk[base + i], k1 = Kk[base + i + 32];
    Kk[base + i]      = k0 * c - k1 * s;
    Kk[base + i + 32] = k1 * c + k0 * s;
}

// ---------------- Causal attention: one wave per (t, h) ----------------
__global__ void attn_kernel(const float* __restrict__ Q, const float* __restrict__ Kc,
                            const float* __restrict__ Vc, float* __restrict__ O) {
    int t = blockIdx.x;
    int h = blockIdx.y;
    int lane = threadIdx.x; // 0..63
    __shared__ float q[DH];
    __shared__ float p[T];
    q[lane] = Q[(size_t)t * D + h * DH + lane];
    __syncthreads();
    int j0 = lane, j1 = lane + 64;
    float s0 = -1e30f, s1 = -1e30f;
    if (j0 <= t) {
        float s = 0.f;
        #pragma unroll
        for (int d = 0; d < DH; ++d) s += q[d] * Kc[(size_t)j0 * D + h * DH + d];
        s0 = s * SCALE;
    }
    if (j1 <= t) {
        float s = 0.f;
        #pragma unroll
        for (int d = 0; d < DH; ++d) s += q[d] * Kc[(size_t)j1 * D + h * DH + d];
        s1 = s * SCALE;
    }
    float m = fmaxf(s0, s1);
    for (int o = 32; o >= 1; o >>= 1) m = fmaxf(m, __shfl_xor(m, o));
    float e0 = (j0 <= t) ? __expf(s0 - m) : 0.f;
    float e1 = (j1 <= t) ? __expf(s1 - m) : 0.f;
    float sum = e0 + e1;
    for (int o = 32; o >= 1; o >>= 1) sum += __shfl_xor(sum, o);
    float inv = 1.f / sum;
    p[j0] = e0 * inv;
    p[j1] = e1 * inv;
    __syncthreads();
    float acc = 0.f;
    int nj = t + 1;
    for (int j = 0; j < nj; ++j) acc += p[j] * Vc[(size_t)j * D + h * DH + lane];
    O[(size_t)t * D + h * DH + lane] = acc;
}

// ---------------- silu(G)*U -> G ----------------
__global__ void silu_mul_kernel(float* __restrict__ G, const float* __restrict__ U, int n) {
    int i = blockIdx.x * 256 + threadIdx.x;
    if (i < n) {
        float g = G[i], u = U[i];
        G[i] = g / (1.f + __expf(-g)) * u;
    }
}

// ---------------- logits: out[v] = emb[v,:] . xl  (one wave per row) ----------------
__global__ void logits_kernel(const float* __restrict__ emb, const float* __restrict__ xl,
                              float* __restrict__ out) {
    __shared__ float x[D];
    int tid = threadIdx.x; // 256
    ((float4*)x)[tid] = ((const float4*)xl)[tid];
    __syncthreads();
    int row = blockIdx.x * 4 + (tid >> 6);
    int lane = tid & 63;
    const float4* e4 = (const float4*)(emb + (size_t)row * D);
    const float4* x4 = (const float4*)x;
    float s = 0.f;
    #pragma unroll
    for (int k = lane; k < D / 4; k += 64) {
        float4 ev = e4[k], xv = x4[k];
        s += ev.x * xv.x + ev.y * xv.y + ev.z * xv.z + ev.w * xv.w;
    }
    for (int o = 32; o >= 1; o >>= 1) s += __shfl_xor(s, o);
    if (lane == 0) out[row] = s;
}

extern "C" void kernel_launch(void* const* d_in, const int* in_sizes, int n_in,
                              void* d_out, int out_size, void* d_ws, size_t ws_size,
                              hipStream_t stream) {
    const int*   ids = (const int*)d_in[0];
    const float* emb = (const float*)d_in[1];
    const float* Wq  = (const float*)d_in[2];
    const float* Wk  = (const float*)d_in[3];
    const float* Wv  = (const float*)d_in[4];
    const float* Wo  = (const float*)d_in[5];
    const float* Wg  = (const float*)d_in[6];
    const float* Wu  = (const float*)d_in[7];
    const float* Wd  = (const float*)d_in[8];
    const float* attn_norm = (const float*)d_in[9];
    const float* ffn_norm  = (const float*)d_in[10];
    const float* norm_out  = (const float*)d_in[11];
    float* out = (float*)d_out;

    float* ws = (float*)d_ws;
    float* X    = ws;                      // T*D
    float* Hn   = X + (size_t)T * D;       // T*D
    float* Qb   = Hn + (size_t)T * D;      // T*D
    float* Kb   = Qb + (size_t)T * D;      // T*D
    float* Vb   = Kb + (size_t)T * D;      // T*D
    float* AO   = Vb + (size_t)T * D;      // T*D
    float* G    = AO + (size_t)T * D;      // T*F
    float* U    = G + (size_t)T * F;       // T*F
    float* cosT = U + (size_t)T * F;       // T*32
    float* sinT = cosT + (size_t)T * 32;   // T*32
    float* xl   = sinT + (size_t)T * 32;   // D

    rope_init_kernel<<<T, 32, 0, stream>>>(cosT, sinT);
    embed_kernel<<<T, 256, 0, stream>>>(ids, emb, X);

    dim3 gblk(16, 16);
    dim3 gridD(D / 32, T / 32);   // N=1024
    dim3 gridF(F / 32, T / 32);   // N=2816

    for (int l = 0; l < L; ++l) {
        const float* wq = Wq + (size_t)l * D * D;
        const float* wk = Wk + (size_t)l * D * D;
        const float* wv = Wv + (size_t)l * D * D;
        const float* wo = Wo + (size_t)l * D * D;
        const float* wg = Wg + (size_t)l * D * F;
        const float* wu = Wu + (size_t)l * D * F;
        const float* wd = Wd + (size_t)l * F * D;

        // attn block
        rmsnorm_kernel<<<T, 256, 0, stream>>>(X, attn_norm + (size_t)l * D, Hn);
        gemm_f32<<<gridD, gblk, 0, stream>>>(Hn, wq, nullptr, Qb, D, D);
        gemm_f32<<<gridD, gblk, 0, stream>>>(Hn, wk, nullptr, Kb, D, D);
        gemm_f32<<<gridD, gblk, 0, stream>>>(Hn, wv, nullptr, Vb, D, D);
        rope_apply_kernel<<<(T * H * 32) / 256, 256, 0, stream>>>(Qb, Kb, cosT, sinT);
        attn_kernel<<<dim3(T, H), 64, 0, stream>>>(Qb, Kb, Vb, AO);
        gemm_f32<<<gridD, gblk, 0, stream>>>(AO, wo, X, X, D, D);  // X += AO @ Wo

        // ffn block
        rmsnorm_kernel<<<T, 256, 0, stream>>>(X, ffn_norm + (size_t)l * D, Hn);
        gemm_f32<<<gridF, gblk, 0, stream>>>(Hn, wg, nullptr, G, F, D);
        gemm_f32<<<gridF, gblk, 0, stream>>>(Hn, wu, nullptr, U, F, D);
        silu_mul_kernel<<<(T * F + 255) / 256, 256, 0, stream>>>(G, U, T * F);
        gemm_f32<<<gridD, gblk, 0, stream>>>(G, wd, X, X, D, F);   // X += silu(G)*U @ Wd
    }

    // final norm of last token + tied-embedding logits
    rmsnorm_kernel<<<1, 256, 0, stream>>>(X + (size_t)(T - 1) * D, norm_out, xl);
    logits_kernel<<<V / 4, 256, 0, stream>>>(emb, xl, out);
}

// Round 2
// 2633.867 us; speedup vs baseline: 2.6097x; 2.6097x over previous
//
#include <hip/hip_runtime.h>
#include <hip/hip_bf16.h>
#include <math.h>

namespace {
constexpr int V = 32000, D = 1024, L = 8, H = 16, T = 128, F = 2816, DH = 64;
constexpr float EPS = 1e-5f;
constexpr float SCALE = 0.125f; // 1/sqrt(DH)
}

typedef __attribute__((ext_vector_type(8))) short short8;
typedef __attribute__((ext_vector_type(4))) float f32x4;

__device__ __forceinline__ unsigned short f2bf(float x) {
    union { float f; unsigned u; } v; v.f = x;
    unsigned r = v.u + 0x7FFFu + ((v.u >> 16) & 1u);
    return (unsigned short)(r >> 16);
}

// ---------------- RoPE tables: cos/sin [T, 32] ----------------
__global__ void rope_init_kernel(float* __restrict__ cosT, float* __restrict__ sinT) {
    int t = blockIdx.x;
    int i = threadIdx.x; // 0..31
    float inv = powf(10000.0f, -(2.0f * (float)i) / (float)DH);
    float ang = (float)t * inv;
    cosT[t * 32 + i] = cosf(ang);
    sinT[t * 32 + i] = sinf(ang);
}

// ---------------- Embedding gather ----------------
__global__ void embed_kernel(const int* __restrict__ ids, const float* __restrict__ emb,
                             float* __restrict__ X) {
    int t = blockIdx.x;
    int id = ids[t];
    float4 v = ((const float4*)(emb + (size_t)id * D))[threadIdx.x];
    ((float4*)(X + (size_t)t * D))[threadIdx.x] = v;
}

// ---------------- RMSNorm -> fp32 (used for final norm) ----------------
__global__ void rmsnorm_f32_kernel(const float* __restrict__ X, const float* __restrict__ w,
                                   float* __restrict__ Y) {
    int t = blockIdx.x;
    int tid = threadIdx.x;
    float4 xv = ((const float4*)(X + (size_t)t * D))[tid];
    float s = xv.x * xv.x + xv.y * xv.y + xv.z * xv.z + xv.w * xv.w;
    for (int o = 32; o >= 1; o >>= 1) s += __shfl_xor(s, o);
    __shared__ float red[4];
    if ((tid & 63) == 0) red[tid >> 6] = s;
    __syncthreads();
    float tot = red[0] + red[1] + red[2] + red[3];
    float r = rsqrtf(tot / (float)D + EPS);
    float4 wv = ((const float4*)w)[tid];
    float4 y;
    y.x = xv.x * r * wv.x; y.y = xv.y * r * wv.y;
    y.z = xv.z * r * wv.z; y.w = xv.w * r * wv.w;
    ((float4*)(Y + (size_t)t * D))[tid] = y;
}

// ---------------- RMSNorm -> bf16 ----------------
__global__ void rmsnorm_bf16_kernel(const float* __restrict__ X, const float* __restrict__ w,
                                    unsigned short* __restrict__ Y) {
    int t = blockIdx.x;
    int tid = threadIdx.x;
    float4 xv = ((const float4*)(X + (size_t)t * D))[tid];
    float s = xv.x * xv.x + xv.y * xv.y + xv.z * xv.z + xv.w * xv.w;
    for (int o = 32; o >= 1; o >>= 1) s += __shfl_xor(s, o);
    __shared__ float red[4];
    if ((tid & 63) == 0) red[tid >> 6] = s;
    __syncthreads();
    float tot = red[0] + red[1] + red[2] + red[3];
    float r = rsqrtf(tot / (float)D + EPS);
    float4 wv = ((const float4*)w)[tid];
    ushort4 y;
    y.x = f2bf(xv.x * r * wv.x); y.y = f2bf(xv.y * r * wv.y);
    y.z = f2bf(xv.z * r * wv.z); y.w = f2bf(xv.w * r * wv.w);
    ((ushort4*)(Y + (size_t)t * D))[tid] = y;
}

// ---------------- 64x64 transpose + fp32->bf16 convert tile ----------------
__device__ __forceinline__ void transpose_tile(const float* __restrict__ src, int srcN,
                                               unsigned short* __restrict__ dst, int dstN) {
    __shared__ float tile[64][65];
    int tx = threadIdx.x & 63, ty = threadIdx.x >> 6;
    #pragma unroll
    for (int r = 0; r < 64; r += 4)
        tile[r + ty][tx] = src[(size_t)(r + ty) * srcN + tx];
    __syncthreads();
    #pragma unroll
    for (int r = 0; r < 64; r += 4)
        dst[(size_t)(r + ty) * dstN + tx] = f2bf(tile[tx][r + ty]);
}

// Wq/Wk/Wv/Wo [L][D][D] -> WqkvoT [L][4][D(n)][D(k)] bf16
__global__ void conv_qkvo_kernel(const float* __restrict__ Wq, const float* __restrict__ Wk,
                                 const float* __restrict__ Wv, const float* __restrict__ Wo,
                                 unsigned short* __restrict__ out) {
    int l = blockIdx.z >> 2, w = blockIdx.z & 3;
    const float* src = (w == 0 ? Wq : w == 1 ? Wk : w == 2 ? Wv : Wo) + (size_t)l * D * D;
    unsigned short* dst = out + ((size_t)(l * 4 + w)) * D * D;
    int n0 = blockIdx.x * 64, k0 = blockIdx.y * 64;
    transpose_tile(src + (size_t)k0 * D + n0, D, dst + (size_t)n0 * D + k0, D);
}

// Wg/Wu [L][D][F] -> WguT [L][2][F(n)][D(k)] bf16
__global__ void conv_gu_kernel(const float* __restrict__ Wg, const float* __restrict__ Wu,
                               unsigned short* __restrict__ out) {
    int l = blockIdx.z >> 1, w = blockIdx.z & 1;
    const float* src = (w ? Wu : Wg) + (size_t)l * D * F;
    unsigned short* dst = out + ((size_t)(l * 2 + w)) * F * D;
    int n0 = blockIdx.x * 64, k0 = blockIdx.y * 64;
    transpose_tile(src + (size_t)k0 * F + n0, F, dst + (size_t)n0 * D + k0, D);
}

// Wd [L][F][D] -> WdT [L][D(n)][F(k)] bf16
__global__ void conv_d_kernel(const float* __restrict__ Wd, unsigned short* __restrict__ out) {
    int l = blockIdx.z;
    const float* src = Wd + (size_t)l * F * D;
    unsigned short* dst = out + (size_t)l * D * F;
    int n0 = blockIdx.x * 64, k0 = blockIdx.y * 64;
    transpose_tile(src + (size_t)k0 * D + n0, D, dst + (size_t)n0 * F + k0, F);
}

// ---------------- MFMA K-loop: one wave computes C[0..127][n16..n16+15] ----------------
// A [128][K] bf16 row-major, Bw = Wt + n16*K where Wt is [N][K] bf16 (pre-transposed).
// Fragment layouts (mfma_f32_16x16x32_bf16): A: lane holds row (l&15), k = 8*(l>>4)+j
// (8 contiguous); B: col (l&15), same k. C/D: col = l&15, row = (l>>4)*4 + reg.
template<int K>
__device__ __forceinline__ void mfma_kloop(const unsigned short* __restrict__ A,
                                           const unsigned short* __restrict__ Bw,
                                           f32x4 acc[8]) {
    int lane = threadIdx.x;
    int lrow = lane & 15;
    int loct = (lane >> 4) << 3;
    const unsigned short* aBase = A + (size_t)lrow * K + loct;
    const unsigned short* bBase = Bw + (size_t)lrow * K + loct;
    #pragma unroll 2
    for (int k0 = 0; k0 < K; k0 += 32) {
        short8 b = *(const short8*)(bBase + k0);
        #pragma unroll
        for (int mf = 0; mf < 8; ++mf) {
            short8 a = *(const short8*)(aBase + (size_t)(mf * 16) * K + k0);
            acc[mf] = __builtin_amdgcn_mfma_f32_16x16x32_bf16(a, b, acc[mf], 0, 0, 0);
        }
    }
}

// QKV: Hn[128][D] @ WqkvoT rows 0..3071 -> QKV buffer [3][T][D] fp32
__global__ void gemm_qkv_kernel(const unsigned short* __restrict__ Hn,
                                const unsigned short* __restrict__ Wt,
                                float* __restrict__ QKV) {
    int n16 = blockIdx.x * 16;
    f32x4 acc[8] = {};
    mfma_kloop<D>(Hn, Wt + (size_t)n16 * D, acc);
    int lane = threadIdx.x;
    int which = n16 >> 10;
    int ncol = (n16 & 1023) + (lane & 15);
    float* outp = QKV + (size_t)which * T * D;
    int rbase = (lane >> 4) * 4;
    #pragma unroll
    for (int mf = 0; mf < 8; ++mf)
        #pragma unroll
        for (int r = 0; r < 4; ++r)
            outp[(size_t)(mf * 16 + rbase + r) * D + ncol] = acc[mf][r];
}

// Residual GEMM: X[128][D] += Abf[128][K] @ Wt[N=1024][K]^T
template<int K>
__global__ void gemm_resid_kernel(const unsigned short* __restrict__ Abf,
                                  const unsigned short* __restrict__ Wt,
                                  float* __restrict__ X) {
    int n16 = blockIdx.x * 16;
    f32x4 acc[8] = {};
    mfma_kloop<K>(Abf, Wt + (size_t)n16 * K, acc);
    int lane = threadIdx.x;
    int ncol = n16 + (lane & 15);
    int rbase = (lane >> 4) * 4;
    #pragma unroll
    for (int mf = 0; mf < 8; ++mf)
        #pragma unroll
        for (int r = 0; r < 4; ++r) {
            size_t idx = (size_t)(mf * 16 + rbase + r) * D + ncol;
            X[idx] += acc[mf][r];
        }
}

// GU fused: g = Hn@Wg, u = Hn@Wu, out = silu(g)*u -> bf16 Gact[128][F]
__global__ void gemm_gu_kernel(const unsigned short* __restrict__ Hn,
                               const unsigned short* __restrict__ Wgu, // [2F][D]
                               unsigned short* __restrict__ Gact) {
    int n16 = blockIdx.x * 16;
    int lane = threadIdx.x;
    int lrow = lane & 15;
    int loct = (lane >> 4) << 3;
    f32x4 ag[8] = {}, au[8] = {};
    const unsigned short* aBase = Hn + (size_t)lrow * D + loct;
    const unsigned short* bg = Wgu + (size_t)(n16 + lrow) * D + loct;
    const unsigned short* bu = bg + (size_t)F * D;
    #pragma unroll 2
    for (int k0 = 0; k0 < D; k0 += 32) {
        short8 vg = *(const short8*)(bg + k0);
        short8 vu = *(const short8*)(bu + k0);
        #pragma unroll
        for (int mf = 0; mf < 8; ++mf) {
            short8 a = *(const short8*)(aBase + (size_t)(mf * 16) * D + k0);
            ag[mf] = __builtin_amdgcn_mfma_f32_16x16x32_bf16(a, vg, ag[mf], 0, 0, 0);
            au[mf] = __builtin_amdgcn_mfma_f32_16x16x32_bf16(a, vu, au[mf], 0, 0, 0);
        }
    }
    int ncol = n16 + lrow;
    int rbase = (lane >> 4) * 4;
    #pragma unroll
    for (int mf = 0; mf < 8; ++mf)
        #pragma unroll
        for (int r = 0; r < 4; ++r) {
            float g = ag[mf][r], u = au[mf][r];
            float sv = g / (1.f + __expf(-g)) * u;
            Gact[(size_t)(mf * 16 + rbase + r) * F + ncol] = f2bf(sv);
        }
}

// ---------------- Attention with fused RoPE, bf16 output ----------------
__global__ void attn_rope_kernel(const float* __restrict__ QKV,
                                 const float* __restrict__ cosT, const float* __restrict__ sinT,
                                 unsigned short* __restrict__ AO) {
    int t = blockIdx.x, h = blockIdx.y, lane = threadIdx.x;
    const float* Qp = QKV;
    const float* Kp = QKV + (size_t)T * D;
    const float* Vp = QKV + (size_t)2 * T * D;
    __shared__ float q[DH];
    __shared__ float p[T];
    float qv = Qp[(size_t)t * D + h * DH + lane];
    float qpart = __shfl_xor(qv, 32);
    {
        int i = lane & 31;
        float c = cosT[t * 32 + i], sn = sinT[t * 32 + i];
        q[lane] = (lane < 32) ? (qv * c - qpart * sn) : (qv * c + qpart * sn);
    }
    __syncthreads();
    int j0 = lane, j1 = lane + 64;
    float s0 = -1e30f, s1 = -1e30f;
    if (j0 <= t) {
        const float* kr = Kp + (size_t)j0 * D + h * DH;
        const float* cr = cosT + j0 * 32;
        const float* sr = sinT + j0 * 32;
        float s = 0.f;
        #pragma unroll 8
        for (int d = 0; d < 32; ++d) {
            float ka = kr[d], kb = kr[d + 32];
            float c = cr[d], sn = sr[d];
            s += q[d] * (ka * c - kb * sn) + q[d + 32] * (kb * c + ka * sn);
        }
        s0 = s * SCALE;
    }
    if (j1 <= t) {
        const float* kr = Kp + (size_t)j1 * D + h * DH;
        const float* cr = cosT + j1 * 32;
        const float* sr = sinT + j1 * 32;
        float s = 0.f;
        #pragma unroll 8
        for (int d = 0; d < 32; ++d) {
            float ka = kr[d], kb = kr[d + 32];
            float c = cr[d], sn = sr[d];
            s += q[d] * (ka * c - kb * sn) + q[d + 32] * (kb * c + ka * sn);
        }
        s1 = s * SCALE;
    }
    float m = fmaxf(s0, s1);
    for (int o = 32; o >= 1; o >>= 1) m = fmaxf(m, __shfl_xor(m, o));
    float e0 = (j0 <= t) ? __expf(s0 - m) : 0.f;
    float e1 = (j1 <= t) ? __expf(s1 - m) : 0.f;
    float sum = e0 + e1;
    for (int o = 32; o >= 1; o >>= 1) sum += __shfl_xor(sum, o);
    float inv = 1.f / sum;
    p[j0] = e0 * inv;
    p[j1] = e1 * inv;
    __syncthreads();
    float acc = 0.f;
    const float* vcol = Vp + h * DH + lane;
    for (int j = 0; j <= t; ++j) acc += p[j] * vcol[(size_t)j * D];
    AO[(size_t)t * D + h * DH + lane] = f2bf(acc);
}

// ---------------- logits: out[v] = emb[v,:] . xl ----------------
__global__ void logits_kernel(const float* __restrict__ emb, const float* __restrict__ xl,
                              float* __restrict__ out) {
    __shared__ float x[D];
    int tid = threadIdx.x;
    ((float4*)x)[tid] = ((const float4*)xl)[tid];
    __syncthreads();
    int row = blockIdx.x * 4 + (tid >> 6);
    int lane = tid & 63;
    const float4* e4 = (const float4*)(emb + (size_t)row * D);
    const float4* x4 = (const float4*)x;
    float s = 0.f;
    #pragma unroll
    for (int k = lane; k < D / 4; k += 64) {
        float4 ev = e4[k], xv = x4[k];
        s += ev.x * xv.x + ev.y * xv.y + ev.z * xv.z + ev.w * xv.w;
    }
    for (int o = 32; o >= 1; o >>= 1) s += __shfl_xor(s, o);
    if (lane == 0) out[row] = s;
}

// =================== fp32 fallback path (round-1, proven) ===================
__global__ void gemm_f32(const float* __restrict__ A, const float* __restrict__ B,
                         const float* __restrict__ Cin, float* __restrict__ C,
                         int N, int K) {
    __shared__ float As[32][33];
    __shared__ float Bs[32][33];
    int tx = threadIdx.x, ty = threadIdx.y;
    int bx = blockIdx.x * 32;
    int by = blockIdx.y * 32;
    int tid = ty * 16 + tx;
    float acc00 = 0.f, acc01 = 0.f, acc10 = 0.f, acc11 = 0.f;
    for (int k0 = 0; k0 < K; k0 += 32) {
        #pragma unroll
        for (int i = tid; i < 32 * 32; i += 256) {
            int r = i >> 5, c = i & 31;
            As[r][c] = A[(size_t)(by + r) * K + (k0 + c)];
            Bs[r][c] = B[(size_t)(k0 + r) * N + (bx + c)];
        }
        __syncthreads();
        #pragma unroll
        for (int kk = 0; kk < 32; ++kk) {
            float a0 = As[ty * 2][kk], a1 = As[ty * 2 + 1][kk];
            float b0 = Bs[kk][tx * 2], b1 = Bs[kk][tx * 2 + 1];
            acc00 = fmaf(a0, b0, acc00);
            acc01 = fmaf(a0, b1, acc01);
            acc10 = fmaf(a1, b0, acc10);
            acc11 = fmaf(a1, b1, acc11);
        }
        __syncthreads();
    }
    int r0 = by + ty * 2, c0 = bx + tx * 2;
    float v00 = acc00, v01 = acc01, v10 = acc10, v11 = acc11;
    if (Cin) {
        v00 += Cin[(size_t)r0 * N + c0];
        v01 += Cin[(size_t)r0 * N + c0 + 1];
        v10 += Cin[(size_t)(r0 + 1) * N + c0];
        v11 += Cin[(size_t)(r0 + 1) * N + c0 + 1];
    }
    C[(size_t)r0 * N + c0] = v00;
    C[(size_t)r0 * N + c0 + 1] = v01;
    C[(size_t)(r0 + 1) * N + c0] = v10;
    C[(size_t)(r0 + 1) * N + c0 + 1] = v11;
}

__global__ void rope_apply_kernel(float* __restrict__ Q, float* __restrict__ Kk,
                                  const float* __restrict__ cosT, const float* __restrict__ sinT) {
    int idx = blockIdx.x * 256 + threadIdx.x;
    int i = idx & 31;
    int h = (idx >> 5) & (H - 1);
    int t = idx >> 9;
    float c = cosT[t * 32 + i], s = sinT[t * 32 + i];
    size_t base = (size_t)t * D + h * DH;
    float q0 = Q[base + i], q1 = Q[base + i + 32];
    Q[base + i]      = q0 * c - q1 * s;
    Q[base + i + 32] = q1 * c + q0 * s;
    float k0 = Kk[base + i], k1 = Kk[base + i + 32];
    Kk[base + i]      = k0 * c - k1 * s;
    Kk[base + i + 32] = k1 * c + k0 * s;
}

__global__ void attn_f32_kernel(const float* __restrict__ Q, const float* __restrict__ Kc,
                                const float* __restrict__ Vc, float* __restrict__ O) {
    int t = blockIdx.x;
    int h = blockIdx.y;
    int lane = threadIdx.x;
    __shared__ float q[DH];
    __shared__ float p[T];
    q[lane] = Q[(size_t)t * D + h * DH + lane];
    __syncthreads();
    int j0 = lane, j1 = lane + 64;
    float s0 = -1e30f, s1 = -1e30f;
    if (j0 <= t) {
        float s = 0.f;
        #pragma unroll
        for (int d = 0; d < DH; ++d) s += q[d] * Kc[(size_t)j0 * D + h * DH + d];
        s0 = s * SCALE;
    }
    if (j1 <= t) {
        float s = 0.f;
        #pragma unroll
        for (int d = 0; d < DH; ++d) s += q[d] * Kc[(size_t)j1 * D + h * DH + d];
        s1 = s * SCALE;
    }
    float m = fmaxf(s0, s1);
    for (int o = 32; o >= 1; o >>= 1) m = fmaxf(m, __shfl_xor(m, o));
    float e0 = (j0 <= t) ? __expf(s0 - m) : 0.f;
    float e1 = (j1 <= t) ? __expf(s1 - m) : 0.f;
    float sum = e0 + e1;
    for (int o = 32; o >= 1; o >>= 1) sum += __shfl_xor(sum, o);
    float inv = 1.f / sum;
    p[j0] = e0 * inv;
    p[j1] = e1 * inv;
    __syncthreads();
    float acc = 0.f;
    for (int j = 0; j <= t; ++j) acc += p[j] * Vc[(size_t)j * D + h * DH + lane];
    O[(size_t)t * D + h * DH + lane] = acc;
}

__global__ void silu_mul_kernel(float* __restrict__ G, const float* __restrict__ U, int n) {
    int i = blockIdx.x * 256 + threadIdx.x;
    if (i < n) {
        float g = G[i], u = U[i];
        G[i] = g / (1.f + __expf(-g)) * u;
    }
}

extern "C" void kernel_launch(void* const* d_in, const int* in_sizes, int n_in,
                              void* d_out, int out_size, void* d_ws, size_t ws_size,
                              hipStream_t stream) {
    const int*   ids = (const int*)d_in[0];
    const float* emb = (const float*)d_in[1];
    const float* Wq  = (const float*)d_in[2];
    const float* Wk  = (const float*)d_in[3];
    const float* Wv  = (const float*)d_in[4];
    const float* Wo  = (const float*)d_in[5];
    const float* Wg  = (const float*)d_in[6];
    const float* Wu  = (const float*)d_in[7];
    const float* Wd  = (const float*)d_in[8];
    const float* attn_norm = (const float*)d_in[9];
    const float* ffn_norm  = (const float*)d_in[10];
    const float* norm_out  = (const float*)d_in[11];
    float* out = (float*)d_out;

    // ---- new-path ws layout ----
    size_t off = 0;
    auto alloc = [&](size_t bytes) {
        void* p = (char*)d_ws + off;
        off += (bytes + 255) & ~(size_t)255;
        return p;
    };
    unsigned short* WqkvoT = (unsigned short*)alloc((size_t)L * 4 * D * D * 2);
    unsigned short* WguT   = (unsigned short*)alloc((size_t)L * 2 * F * D * 2);
    unsigned short* WdT    = (unsigned short*)alloc((size_t)L * D * F * 2);
    float*          X      = (float*)alloc((size_t)T * D * 4);
    float*          QKV    = (float*)alloc((size_t)3 * T * D * 4);
    float*          cosT   = (float*)alloc((size_t)T * 32 * 4);
    float*          sinT   = (float*)alloc((size_t)T * 32 * 4);
    float*          xl     = (float*)alloc((size_t)D * 4);
    unsigned short* Hn_bf  = (unsigned short*)alloc((size_t)T * D * 2);
    unsigned short* AO_bf  = (unsigned short*)alloc((size_t)T * D * 2);
    unsigned short* Gact   = (unsigned short*)alloc((size_t)T * F * 2);
    size_t need = off;

    if (ws_size >= need) {
        // ================= bf16 MFMA path =================
        conv_qkvo_kernel<<<dim3(D / 64, D / 64, L * 4), 256, 0, stream>>>(Wq, Wk, Wv, Wo, WqkvoT);
        conv_gu_kernel<<<dim3(F / 64, D / 64, L * 2), 256, 0, stream>>>(Wg, Wu, WguT);
        conv_d_kernel<<<dim3(D / 64, F / 64, L), 256, 0, stream>>>(Wd, WdT);
        rope_init_kernel<<<T, 32, 0, stream>>>(cosT, sinT);
        embed_kernel<<<T, 256, 0, stream>>>(ids, emb, X);

        for (int l = 0; l < L; ++l) {
            const unsigned short* wqkvo = WqkvoT + (size_t)l * 4 * D * D;
            const unsigned short* wgu   = WguT + (size_t)l * 2 * F * D;
            const unsigned short* wd    = WdT + (size_t)l * D * F;

            rmsnorm_bf16_kernel<<<T, 256, 0, stream>>>(X, attn_norm + (size_t)l * D, Hn_bf);
            gemm_qkv_kernel<<<3 * D / 16, 64, 0, stream>>>(Hn_bf, wqkvo, QKV);
            attn_rope_kernel<<<dim3(T, H), 64, 0, stream>>>(QKV, cosT, sinT, AO_bf);
            gemm_resid_kernel<D><<<D / 16, 64, 0, stream>>>(AO_bf, wqkvo + (size_t)3 * D * D, X);
            rmsnorm_bf16_kernel<<<T, 256, 0, stream>>>(X, ffn_norm + (size_t)l * D, Hn_bf);
            gemm_gu_kernel<<<F / 16, 64, 0, stream>>>(Hn_bf, wgu, Gact);
            gemm_resid_kernel<F><<<D / 16, 64, 0, stream>>>(Gact, wd, X);
        }
        rmsnorm_f32_kernel<<<1, 256, 0, stream>>>(X + (size_t)(T - 1) * D, norm_out, xl);
        logits_kernel<<<V / 4, 256, 0, stream>>>(emb, xl, out);
    } else {
        // ================= fp32 fallback (round-1) =================
        float* ws = (float*)d_ws;
        float* Xf   = ws;
        float* Hn   = Xf + (size_t)T * D;
        float* Qb   = Hn + (size_t)T * D;
        float* Kb   = Qb + (size_t)T * D;
        float* Vb   = Kb + (size_t)T * D;
        float* AOf  = Vb + (size_t)T * D;
        float* G    = AOf + (size_t)T * D;
        float* U    = G + (size_t)T * F;
        float* cosF = U + (size_t)T * F;
        float* sinF = cosF + (size_t)T * 32;
        float* xlf  = sinF + (size_t)T * 32;

        rope_init_kernel<<<T, 32, 0, stream>>>(cosF, sinF);
        embed_kernel<<<T, 256, 0, stream>>>(ids, emb, Xf);

        dim3 gblk(16, 16);
        dim3 gridD(D / 32, T / 32);
        dim3 gridF(F / 32, T / 32);

        for (int l = 0; l < L; ++l) {
            const float* wq = Wq + (size_t)l * D * D;
            const float* wk = Wk + (size_t)l * D * D;
            const float* wv = Wv + (size_t)l * D * D;
            const float* wo = Wo + (size_t)l * D * D;
            const float* wg = Wg + (size_t)l * D * F;
            const float* wu = Wu + (size_t)l * D * F;
            const float* wd = Wd + (size_t)l * F * D;

            rmsnorm_f32_kernel<<<T, 256, 0, stream>>>(Xf, attn_norm + (size_t)l * D, Hn);
            gemm_f32<<<gridD, gblk, 0, stream>>>(Hn, wq, nullptr, Qb, D, D);
            gemm_f32<<<gridD, gblk, 0, stream>>>(Hn, wk, nullptr, Kb, D, D);
            gemm_f32<<<gridD, gblk, 0, stream>>>(Hn, wv, nullptr, Vb, D, D);
            rope_apply_kernel<<<(T * H * 32) / 256, 256, 0, stream>>>(Qb, Kb, cosF, sinF);
            attn_f32_kernel<<<dim3(T, H), 64, 0, stream>>>(Qb, Kb, Vb, AOf);
            gemm_f32<<<gridD, gblk, 0, stream>>>(AOf, wo, Xf, Xf, D, D);
            rmsnorm_f32_kernel<<<T, 256, 0, stream>>>(Xf, ffn_norm + (size_t)l * D, Hn);
            gemm_f32<<<gridF, gblk, 0, stream>>>(Hn, wg, nullptr, G, F, D);
            gemm_f32<<<gridF, gblk, 0, stream>>>(Hn, wu, nullptr, U, F, D);
            silu_mul_kernel<<<(T * F + 255) / 256, 256, 0, stream>>>(G, U, T * F);
            gemm_f32<<<gridD, gblk, 0, stream>>>(G, wd, Xf, Xf, D, F);
        }
        rmsnorm_f32_kernel<<<1, 256, 0, stream>>>(Xf + (size_t)(T - 1) * D, norm_out, xlf);
        logits_kernel<<<V / 4, 256, 0, stream>>>(emb, xlf, out);
    }
}

// Round 3
// 1007.355 us; speedup vs baseline: 6.8235x; 2.6146x over previous
//
#include <hip/hip_runtime.h>
#include <hip/hip_bf16.h>
#include <math.h>

namespace {
constexpr int V = 32000, D = 1024, L = 8, H = 16, T = 128, F = 2816, DH = 64;
constexpr float EPS = 1e-5f;
constexpr float SCALE = 0.125f; // 1/sqrt(DH)
constexpr int QKVN = 3 * D;     // 3072
constexpr int GUN  = 2 * F;     // 5632
}

typedef __attribute__((ext_vector_type(8))) short short8;
typedef __attribute__((ext_vector_type(4))) float f32x4;

__device__ __forceinline__ unsigned short f2bf(float x) {
    union { float f; unsigned u; } v; v.f = x;
    unsigned r = v.u + 0x7FFFu + ((v.u >> 16) & 1u);
    return (unsigned short)(r >> 16);
}

// ---------------- RoPE tables: cos/sin [T, 32] ----------------
__global__ void rope_init_kernel(float* __restrict__ cosT, float* __restrict__ sinT) {
    int t = blockIdx.x;
    int i = threadIdx.x; // 0..31
    float inv = powf(10000.0f, -(2.0f * (float)i) / (float)DH);
    float ang = (float)t * inv;
    cosT[t * 32 + i] = cosf(ang);
    sinT[t * 32 + i] = sinf(ang);
}

// ---------------- Embedding gather ----------------
__global__ void embed_kernel(const int* __restrict__ ids, const float* __restrict__ emb,
                             float* __restrict__ X) {
    int t = blockIdx.x;
    int id = ids[t];
    float4 v = ((const float4*)(emb + (size_t)id * D))[threadIdx.x];
    ((float4*)(X + (size_t)t * D))[threadIdx.x] = v;
}

// ---------------- RMSNorm -> fp32 ----------------
__global__ void rmsnorm_f32_kernel(const float* __restrict__ X, const float* __restrict__ w,
                                   float* __restrict__ Y) {
    int t = blockIdx.x;
    int tid = threadIdx.x;
    float4 xv = ((const float4*)(X + (size_t)t * D))[tid];
    float s = xv.x * xv.x + xv.y * xv.y + xv.z * xv.z + xv.w * xv.w;
    for (int o = 32; o >= 1; o >>= 1) s += __shfl_xor(s, o);
    __shared__ float red[4];
    if ((tid & 63) == 0) red[tid >> 6] = s;
    __syncthreads();
    float tot = red[0] + red[1] + red[2] + red[3];
    float r = rsqrtf(tot / (float)D + EPS);
    float4 wv = ((const float4*)w)[tid];
    float4 y;
    y.x = xv.x * r * wv.x; y.y = xv.y * r * wv.y;
    y.z = xv.z * r * wv.z; y.w = xv.w * r * wv.w;
    ((float4*)(Y + (size_t)t * D))[tid] = y;
}

// ---------------- RMSNorm -> bf16 ----------------
__global__ void rmsnorm_bf16_kernel(const float* __restrict__ X, const float* __restrict__ w,
                                    unsigned short* __restrict__ Y) {
    int t = blockIdx.x;
    int tid = threadIdx.x;
    float4 xv = ((const float4*)(X + (size_t)t * D))[tid];
    float s = xv.x * xv.x + xv.y * xv.y + xv.z * xv.z + xv.w * xv.w;
    for (int o = 32; o >= 1; o >>= 1) s += __shfl_xor(s, o);
    __shared__ float red[4];
    if ((tid & 63) == 0) red[tid >> 6] = s;
    __syncthreads();
    float tot = red[0] + red[1] + red[2] + red[3];
    float r = rsqrtf(tot / (float)D + EPS);
    float4 wv = ((const float4*)w)[tid];
    ushort4 y;
    y.x = f2bf(xv.x * r * wv.x); y.y = f2bf(xv.y * r * wv.y);
    y.z = f2bf(xv.z * r * wv.z); y.w = f2bf(xv.w * r * wv.w);
    ((ushort4*)(Y + (size_t)t * D))[tid] = y;
}

// ---------------- 64x64 transpose + fp32->bf16 convert tile ----------------
__device__ __forceinline__ void transpose_tile(const float* __restrict__ src, int srcN,
                                               unsigned short* __restrict__ dst, int dstN) {
    __shared__ float tile[64][65];
    int tx = threadIdx.x & 63, ty = threadIdx.x >> 6;
    #pragma unroll
    for (int r = 0; r < 64; r += 4)
        tile[r + ty][tx] = src[(size_t)(r + ty) * srcN + tx];
    __syncthreads();
    #pragma unroll
    for (int r = 0; r < 64; r += 4)
        dst[(size_t)(r + ty) * dstN + tx] = f2bf(tile[tx][r + ty]);
}

// Wq/Wk/Wv/Wo [L][D][D] -> WqkvoT [L][4][D(n)][D(k)] bf16
__global__ void conv_qkvo_kernel(const float* __restrict__ Wq, const float* __restrict__ Wk,
                                 const float* __restrict__ Wv, const float* __restrict__ Wo,
                                 unsigned short* __restrict__ out) {
    int l = blockIdx.z >> 2, w = blockIdx.z & 3;
    const float* src = (w == 0 ? Wq : w == 1 ? Wk : w == 2 ? Wv : Wo) + (size_t)l * D * D;
    unsigned short* dst = out + ((size_t)(l * 4 + w)) * D * D;
    int n0 = blockIdx.x * 64, k0 = blockIdx.y * 64;
    transpose_tile(src + (size_t)k0 * D + n0, D, dst + (size_t)n0 * D + k0, D);
}

// Wg/Wu [L][D][F] -> WguT [L][2][F(n)][D(k)] bf16
__global__ void conv_gu_kernel(const float* __restrict__ Wg, const float* __restrict__ Wu,
                               unsigned short* __restrict__ out) {
    int l = blockIdx.z >> 1, w = blockIdx.z & 1;
    const float* src = (w ? Wu : Wg) + (size_t)l * D * F;
    unsigned short* dst = out + ((size_t)(l * 2 + w)) * F * D;
    int n0 = blockIdx.x * 64, k0 = blockIdx.y * 64;
    transpose_tile(src + (size_t)k0 * F + n0, F, dst + (size_t)n0 * D + k0, D);
}

// Wd [L][F][D] -> WdT [L][D(n)][F(k)] bf16
__global__ void conv_d_kernel(const float* __restrict__ Wd, unsigned short* __restrict__ out) {
    int l = blockIdx.z;
    const float* src = Wd + (size_t)l * F * D;
    unsigned short* dst = out + (size_t)l * D * F;
    int n0 = blockIdx.x * 64, k0 = blockIdx.y * 64;
    transpose_tile(src + (size_t)k0 * D + n0, D, dst + (size_t)n0 * F + k0, F);
}

// ---------------- Generic split-K MFMA GEMM ----------------
// out[M=128][ldo] (+)= A[128][lda] @ Wt[N][K]^T, K-chunk CH per blockIdx.y,
// M-range MF*16 rows starting at blockIdx.z*MF*16, 4 waves/block (16 cols each).
// Partials combined with fp32 atomicAdd; caller zero-inits out (or uses residual).
template<int K, int CH, int MF>
__global__ void gemm_split_kernel(const unsigned short* __restrict__ A,
                                  const unsigned short* __restrict__ Wt,
                                  float* __restrict__ out, int ldo) {
    int wave = threadIdx.x >> 6;
    int lane = threadIdx.x & 63;
    int n16 = (blockIdx.x * 4 + wave) * 16;
    int k0 = blockIdx.y * CH;
    int m0 = blockIdx.z * (MF * 16);
    int lrow = lane & 15;
    int loct = (lane >> 4) << 3;
    const unsigned short* aBase = A + (size_t)(m0 + lrow) * K + k0 + loct;
    const unsigned short* bBase = Wt + (size_t)(n16 + lrow) * K + k0 + loct;
    f32x4 acc[MF] = {};
    #pragma unroll 2
    for (int k = 0; k < CH; k += 32) {
        short8 b = *(const short8*)(bBase + k);
        #pragma unroll
        for (int mf = 0; mf < MF; ++mf) {
            short8 a = *(const short8*)(aBase + (size_t)(mf * 16) * K + k);
            acc[mf] = __builtin_amdgcn_mfma_f32_16x16x32_bf16(a, b, acc[mf], 0, 0, 0);
        }
    }
    int ncol = n16 + lrow;
    int rbase = (lane >> 4) * 4;
    #pragma unroll
    for (int mf = 0; mf < MF; ++mf)
        #pragma unroll
        for (int r = 0; r < 4; ++r)
            atomicAdd(&out[(size_t)(m0 + mf * 16 + rbase + r) * ldo + ncol], acc[mf][r]);
}

// ---------------- silu(g)*u from GU[128][2F] fp32 -> Gact[128][F] bf16 ----------------
__global__ void silu_mul_bf16_kernel(const float* __restrict__ GU,
                                     unsigned short* __restrict__ Gact) {
    int t = blockIdx.y;
    int f = blockIdx.x * 256 + threadIdx.x;
    float g = GU[(size_t)t * GUN + f];
    float u = GU[(size_t)t * GUN + F + f];
    Gact[(size_t)t * F + f] = f2bf(g / (1.f + __expf(-g)) * u);
}

// ---------------- Attention with fused RoPE; QKV is [T][3072] fp32 ----------------
__global__ void attn_rope_kernel(const float* __restrict__ QKV,
                                 const float* __restrict__ cosT, const float* __restrict__ sinT,
                                 unsigned short* __restrict__ AO) {
    int t = blockIdx.x, h = blockIdx.y, lane = threadIdx.x;
    __shared__ float q[DH];
    __shared__ float p[T];
    float qv = QKV[(size_t)t * QKVN + h * DH + lane];
    float qpart = __shfl_xor(qv, 32);
    {
        int i = lane & 31;
        float c = cosT[t * 32 + i], sn = sinT[t * 32 + i];
        q[lane] = (lane < 32) ? (qv * c - qpart * sn) : (qv * c + qpart * sn);
    }
    __syncthreads();
    int j0 = lane, j1 = lane + 64;
    float s0 = -1e30f, s1 = -1e30f;
    if (j0 <= t) {
        const float* kr = QKV + (size_t)j0 * QKVN + D + h * DH;
        const float* cr = cosT + j0 * 32;
        const float* sr = sinT + j0 * 32;
        float s = 0.f;
        #pragma unroll 8
        for (int d = 0; d < 32; ++d) {
            float ka = kr[d], kb = kr[d + 32];
            float c = cr[d], sn = sr[d];
            s += q[d] * (ka * c - kb * sn) + q[d + 32] * (kb * c + ka * sn);
        }
        s0 = s * SCALE;
    }
    if (j1 <= t) {
        const float* kr = QKV + (size_t)j1 * QKVN + D + h * DH;
        const float* cr = cosT + j1 * 32;
        const float* sr = sinT + j1 * 32;
        float s = 0.f;
        #pragma unroll 8
        for (int d = 0; d < 32; ++d) {
            float ka = kr[d], kb = kr[d + 32];
            float c = cr[d], sn = sr[d];
            s += q[d] * (ka * c - kb * sn) + q[d + 32] * (kb * c + ka * sn);
        }
        s1 = s * SCALE;
    }
    float m = fmaxf(s0, s1);
    for (int o = 32; o >= 1; o >>= 1) m = fmaxf(m, __shfl_xor(m, o));
    float e0 = (j0 <= t) ? __expf(s0 - m) : 0.f;
    float e1 = (j1 <= t) ? __expf(s1 - m) : 0.f;
    float sum = e0 + e1;
    for (int o = 32; o >= 1; o >>= 1) sum += __shfl_xor(sum, o);
    float inv = 1.f / sum;
    p[j0] = e0 * inv;
    p[j1] = e1 * inv;
    __syncthreads();
    float acc = 0.f;
    const float* vcol = QKV + 2 * D + h * DH + lane;
    for (int j = 0; j <= t; ++j) acc += p[j] * vcol[(size_t)j * QKVN];
    AO[(size_t)t * D + h * DH + lane] = f2bf(acc);
}

// ---------------- logits: out[v] = emb[v,:] . xl ----------------
__global__ void logits_kernel(const float* __restrict__ emb, const float* __restrict__ xl,
                              float* __restrict__ out) {
    __shared__ float x[D];
    int tid = threadIdx.x;
    ((float4*)x)[tid] = ((const float4*)xl)[tid];
    __syncthreads();
    int row = blockIdx.x * 4 + (tid >> 6);
    int lane = tid & 63;
    const float4* e4 = (const float4*)(emb + (size_t)row * D);
    const float4* x4 = (const float4*)x;
    float s = 0.f;
    #pragma unroll
    for (int k = lane; k < D / 4; k += 64) {
        float4 ev = e4[k], xv = x4[k];
        s += ev.x * xv.x + ev.y * xv.y + ev.z * xv.z + ev.w * xv.w;
    }
    for (int o = 32; o >= 1; o >>= 1) s += __shfl_xor(s, o);
    if (lane == 0) out[row] = s;
}

extern "C" void kernel_launch(void* const* d_in, const int* in_sizes, int n_in,
                              void* d_out, int out_size, void* d_ws, size_t ws_size,
                              hipStream_t stream) {
    const int*   ids = (const int*)d_in[0];
    const float* emb = (const float*)d_in[1];
    const float* Wq  = (const float*)d_in[2];
    const float* Wk  = (const float*)d_in[3];
    const float* Wv  = (const float*)d_in[4];
    const float* Wo  = (const float*)d_in[5];
    const float* Wg  = (const float*)d_in[6];
    const float* Wu  = (const float*)d_in[7];
    const float* Wd  = (const float*)d_in[8];
    const float* attn_norm = (const float*)d_in[9];
    const float* ffn_norm  = (const float*)d_in[10];
    const float* norm_out  = (const float*)d_in[11];
    float* out = (float*)d_out;

    size_t off = 0;
    auto alloc = [&](size_t bytes) {
        void* p = (char*)d_ws + off;
        off += (bytes + 255) & ~(size_t)255;
        return p;
    };
    unsigned short* WqkvoT = (unsigned short*)alloc((size_t)L * 4 * D * D * 2);
    unsigned short* WguT   = (unsigned short*)alloc((size_t)L * 2 * F * D * 2);
    unsigned short* WdT    = (unsigned short*)alloc((size_t)L * D * F * 2);
    float*          X      = (float*)alloc((size_t)T * D * 4);
    float*          QKV    = (float*)alloc((size_t)T * QKVN * 4);
    float*          GU     = (float*)alloc((size_t)T * GUN * 4);
    float*          cosT   = (float*)alloc((size_t)T * 32 * 4);
    float*          sinT   = (float*)alloc((size_t)T * 32 * 4);
    float*          xl     = (float*)alloc((size_t)D * 4);
    unsigned short* Hn_bf  = (unsigned short*)alloc((size_t)T * D * 2);
    unsigned short* AO_bf  = (unsigned short*)alloc((size_t)T * D * 2);
    unsigned short* Gact   = (unsigned short*)alloc((size_t)T * F * 2);

    // one-time (per call) weight convert/transpose to bf16 [N][K]
    conv_qkvo_kernel<<<dim3(D / 64, D / 64, L * 4), 256, 0, stream>>>(Wq, Wk, Wv, Wo, WqkvoT);
    conv_gu_kernel<<<dim3(F / 64, D / 64, L * 2), 256, 0, stream>>>(Wg, Wu, WguT);
    conv_d_kernel<<<dim3(D / 64, F / 64, L), 256, 0, stream>>>(Wd, WdT);
    rope_init_kernel<<<T, 32, 0, stream>>>(cosT, sinT);
    embed_kernel<<<T, 256, 0, stream>>>(ids, emb, X);

    for (int l = 0; l < L; ++l) {
        const unsigned short* wqkvo = WqkvoT + (size_t)l * 4 * D * D;
        const unsigned short* wo    = wqkvo + (size_t)3 * D * D;
        const unsigned short* wgu   = WguT + (size_t)l * 2 * F * D;
        const unsigned short* wd    = WdT + (size_t)l * D * F;

        // ---- attention block ----
        rmsnorm_bf16_kernel<<<T, 256, 0, stream>>>(X, attn_norm + (size_t)l * D, Hn_bf);
        hipMemsetAsync(QKV, 0, (size_t)T * QKVN * 4, stream);
        // QKV: N=3072, K=1024, chunks of 256 -> grid(48,4,1), MF=8
        gemm_split_kernel<D, 256, 8><<<dim3(QKVN / 64, 4, 1), 256, 0, stream>>>(
            Hn_bf, wqkvo, QKV, QKVN);
        attn_rope_kernel<<<dim3(T, H), 64, 0, stream>>>(QKV, cosT, sinT, AO_bf);
        // O-proj residual: N=1024, K=1024 -> grid(16,4,2), MF=4, atomic onto X
        gemm_split_kernel<D, 256, 4><<<dim3(D / 64, 4, 2), 256, 0, stream>>>(
            AO_bf, wo, X, D);

        // ---- ffn block ----
        rmsnorm_bf16_kernel<<<T, 256, 0, stream>>>(X, ffn_norm + (size_t)l * D, Hn_bf);
        hipMemsetAsync(GU, 0, (size_t)T * GUN * 4, stream);
        // G,U: N=5632, K=1024 -> grid(88,4,1), MF=8
        gemm_split_kernel<D, 256, 8><<<dim3(GUN / 64, 4, 1), 256, 0, stream>>>(
            Hn_bf, wgu, GU, GUN);
        silu_mul_bf16_kernel<<<dim3(F / 256, T), 256, 0, stream>>>(GU, Gact);
        // down-proj residual: N=1024, K=2816, chunks of 352 -> grid(16,8,2), MF=4
        gemm_split_kernel<F, 352, 4><<<dim3(D / 64, 8, 2), 256, 0, stream>>>(
            Gact, wd, X, D);
    }

    rmsnorm_f32_kernel<<<1, 256, 0, stream>>>(X + (size_t)(T - 1) * D, norm_out, xl);
    logits_kernel<<<V / 4, 256, 0, stream>>>(emb, xl, out);
}

// Round 4
// 852.770 us; speedup vs baseline: 8.0604x; 1.1813x over previous
//
#include <hip/hip_runtime.h>
#include <hip/hip_bf16.h>
#include <math.h>

namespace {
constexpr int V = 32000, D = 1024, L = 8, H = 16, T = 128, F = 2816, DH = 64;
constexpr float EPS = 1e-5f;
constexpr float SCALE = 0.125f; // 1/sqrt(DH)
constexpr int QKVN = 3 * D;     // 3072
constexpr int GUN  = 2 * F;     // 5632
constexpr int NP_O = 4;         // split-K chunks for O-proj (K=1024)
constexpr int NP_D = 11;        // split-K chunks for Wd (K=2816 = 11*256)
}

typedef __attribute__((ext_vector_type(8))) short short8;
typedef __attribute__((ext_vector_type(4))) float f32x4;

__device__ __forceinline__ unsigned short f2bf(float x) {
    union { float f; unsigned u; } v; v.f = x;
    unsigned r = v.u + 0x7FFFu + ((v.u >> 16) & 1u);
    return (unsigned short)(r >> 16);
}

// ---------------- Embedding gather + RoPE tables (fused) ----------------
__global__ void embed_rope_kernel(const int* __restrict__ ids, const float* __restrict__ emb,
                                  float* __restrict__ X,
                                  float* __restrict__ cosT, float* __restrict__ sinT) {
    int t = blockIdx.x, tid = threadIdx.x;
    int id = ids[t];
    ((float4*)(X + (size_t)t * D))[tid] = ((const float4*)(emb + (size_t)id * D))[tid];
    if (tid < 32) {
        float inv = powf(10000.0f, -(2.0f * (float)tid) / (float)DH);
        float ang = (float)t * inv;
        cosT[t * 32 + tid] = cosf(ang);
        sinT[t * 32 + tid] = sinf(ang);
    }
}

// ---------------- RMSNorm with partial-sum reduction + residual X update ----------------
// X[t,:] += sum_c P[c][t,:]  (np partial buffers, chunk stride T*D), then
// Y[t,:] = norm(X[t,:]) * w  (bf16 or fp32 out).
template<bool BF16OUT>
__launch_bounds__(256)
__global__ void rmsnorm_sum_kernel(float* __restrict__ X, const float* __restrict__ P, int np,
                                   const float* __restrict__ w, void* __restrict__ Y) {
    int t = blockIdx.x, tid = threadIdx.x;
    float4 xv = ((float4*)(X + (size_t)t * D))[tid];
    for (int c = 0; c < np; ++c) {
        float4 pv = ((const float4*)(P + (size_t)c * T * D + (size_t)t * D))[tid];
        xv.x += pv.x; xv.y += pv.y; xv.z += pv.z; xv.w += pv.w;
    }
    if (np) ((float4*)(X + (size_t)t * D))[tid] = xv;
    float s = xv.x * xv.x + xv.y * xv.y + xv.z * xv.z + xv.w * xv.w;
    for (int o = 32; o >= 1; o >>= 1) s += __shfl_xor(s, o);
    __shared__ float red[4];
    if ((tid & 63) == 0) red[tid >> 6] = s;
    __syncthreads();
    float tot = red[0] + red[1] + red[2] + red[3];
    float r = rsqrtf(tot / (float)D + EPS);
    float4 wv = ((const float4*)w)[tid];
    if (BF16OUT) {
        ushort4 y;
        y.x = f2bf(xv.x * r * wv.x); y.y = f2bf(xv.y * r * wv.y);
        y.z = f2bf(xv.z * r * wv.z); y.w = f2bf(xv.w * r * wv.w);
        ((ushort4*)((unsigned short*)Y + (size_t)t * D))[tid] = y;
    } else {
        float4 y;
        y.x = xv.x * r * wv.x; y.y = xv.y * r * wv.y;
        y.z = xv.z * r * wv.z; y.w = xv.w * r * wv.w;
        ((float4*)((float*)Y + (size_t)t * D))[tid] = y;
    }
}

// ---------------- MFMA GEMM reading fp32 weights in original [K][N] layout ----------------
// out[128][ldo] = A[128][lda-bf16] @ W[K][N] for K-chunk blockIdx.y (CH wide),
// cols n16..n16+15 of W (selected by blockIdx.z among W0/W1/W2, out col += z*zColOff).
// B tile staged fp32->bf16 through XOR-swizzled LDS, double-buffered, stages of 128 k.
// 4 waves, each owning m-frags {w, w+4} (rows w*16.. and w*16+64..). Plain stores.
template<int CH>
__launch_bounds__(256)
__global__ void gemm_wf32_kernel(const unsigned short* __restrict__ A, int lda,
                                 const float* __restrict__ W0, const float* __restrict__ W1,
                                 const float* __restrict__ W2, int ldw,
                                 float* __restrict__ out, int ldo, int zColOff,
                                 size_t chunkStride) {
    constexpr int STAGES = CH / 128;
    __shared__ unsigned short Bst[2][16 * 128];  // [buf][n*128 + k], 4 KB each
    const float* W = blockIdx.z == 0 ? W0 : (blockIdx.z == 1 ? W1 : W2);
    int tid = threadIdx.x;
    int wave = tid >> 6, lane = tid & 63;
    int n16 = blockIdx.x * 16;
    int k0 = blockIdx.y * CH;

    // B stage-loader: thread -> (col bn, k-octet bko); 16B LDS unit XOR-swizzled by col
    int bn = tid & 15;
    int bko = tid >> 4;  // 0..15
    const float* wBase = W + (size_t)(k0 + bko * 8) * ldw + n16 + bn;
    unsigned short* wPtr = &Bst[0][bn * 128 + ((bko ^ bn) << 3)];

    // compute-side fragment indices
    int lrow = lane & 15;   // A row within frag / B col
    int lqo = lane >> 4;    // k-quarter
    const unsigned short* aB0 = A + (size_t)(wave * 16 + lrow) * lda + k0 + lqo * 8;
    const unsigned short* aB1 = aB0 + (size_t)64 * lda;
    f32x4 acc0 = {}, acc1 = {};

    // prologue: stage 0 -> buf0
    {
        float cur[8];
        #pragma unroll
        for (int j = 0; j < 8; ++j) cur[j] = wBase[(size_t)j * ldw];
        short8 bv;
        #pragma unroll
        for (int j = 0; j < 8; ++j) bv[j] = (short)f2bf(cur[j]);
        *(short8*)wPtr = bv;
    }
    __syncthreads();

    #pragma unroll
    for (int s = 0; s < STAGES; ++s) {
        float nxt[8];
        if (s + 1 < STAGES) {
            const float* wp = wBase + (size_t)(s + 1) * 128 * ldw;
            #pragma unroll
            for (int j = 0; j < 8; ++j) nxt[j] = wp[(size_t)j * ldw];
        }
        const unsigned short* rd = &Bst[s & 1][0];
        #pragma unroll
        for (int ks = 0; ks < 4; ++ks) {
            int u = (ks * 4 + lqo) ^ lrow;
            short8 b = *(const short8*)(rd + lrow * 128 + u * 8);
            short8 a0 = *(const short8*)(aB0 + s * 128 + ks * 32);
            short8 a1 = *(const short8*)(aB1 + s * 128 + ks * 32);
            acc0 = __builtin_amdgcn_mfma_f32_16x16x32_bf16(a0, b, acc0, 0, 0, 0);
            acc1 = __builtin_amdgcn_mfma_f32_16x16x32_bf16(a1, b, acc1, 0, 0, 0);
        }
        if (s + 1 < STAGES) {
            __syncthreads();  // all waves done reading buf[(s+1)&1] (stage s-1)
            short8 bv;
            #pragma unroll
            for (int j = 0; j < 8; ++j) bv[j] = (short)f2bf(nxt[j]);
            *(short8*)(wPtr + ((s & 1) ? 0 : 2048)) = bv;  // -> buf[(s+1)&1]
            __syncthreads();
        }
    }

    int col = zColOff * blockIdx.z + n16 + lrow;
    float* op = out + blockIdx.y * chunkStride;
    int r0 = wave * 16 + lqo * 4;
    #pragma unroll
    for (int r = 0; r < 4; ++r) {
        op[(size_t)(r0 + r) * ldo + col] = acc0[r];
        op[(size_t)(r0 + 64 + r) * ldo + col] = acc1[r];
    }
}

// ---------------- silu(g)*u from GU[128][5632] fp32 -> Gact[128][F] bf16 ----------------
__launch_bounds__(256)
__global__ void silu_mul_bf16_kernel(const float* __restrict__ GU,
                                     unsigned short* __restrict__ Gact) {
    int t = blockIdx.y;
    int f = blockIdx.x * 256 + threadIdx.x;
    float g = GU[(size_t)t * GUN + f];
    float u = GU[(size_t)t * GUN + F + f];
    Gact[(size_t)t * F + f] = f2bf(g / (1.f + __expf(-g)) * u);
}

// ---------------- Attention with fused RoPE; QKV is [T][3072] fp32 ----------------
__global__ void attn_rope_kernel(const float* __restrict__ QKV,
                                 const float* __restrict__ cosT, const float* __restrict__ sinT,
                                 unsigned short* __restrict__ AO) {
    int t = blockIdx.x, h = blockIdx.y, lane = threadIdx.x;
    __shared__ float q[DH];
    __shared__ float p[T];
    float qv = QKV[(size_t)t * QKVN + h * DH + lane];
    float qpart = __shfl_xor(qv, 32);
    {
        int i = lane & 31;
        float c = cosT[t * 32 + i], sn = sinT[t * 32 + i];
        q[lane] = (lane < 32) ? (qv * c - qpart * sn) : (qv * c + qpart * sn);
    }
    __syncthreads();
    int j0 = lane, j1 = lane + 64;
    float s0 = -1e30f, s1 = -1e30f;
    if (j0 <= t) {
        const float* kr = QKV + (size_t)j0 * QKVN + D + h * DH;
        const float* cr = cosT + j0 * 32;
        const float* sr = sinT + j0 * 32;
        float s = 0.f;
        #pragma unroll 8
        for (int d = 0; d < 32; ++d) {
            float ka = kr[d], kb = kr[d + 32];
            float c = cr[d], sn = sr[d];
            s += q[d] * (ka * c - kb * sn) + q[d + 32] * (kb * c + ka * sn);
        }
        s0 = s * SCALE;
    }
    if (j1 <= t) {
        const float* kr = QKV + (size_t)j1 * QKVN + D + h * DH;
        const float* cr = cosT + j1 * 32;
        const float* sr = sinT + j1 * 32;
        float s = 0.f;
        #pragma unroll 8
        for (int d = 0; d < 32; ++d) {
            float ka = kr[d], kb = kr[d + 32];
            float c = cr[d], sn = sr[d];
            s += q[d] * (ka * c - kb * sn) + q[d + 32] * (kb * c + ka * sn);
        }
        s1 = s * SCALE;
    }
    float m = fmaxf(s0, s1);
    for (int o = 32; o >= 1; o >>= 1) m = fmaxf(m, __shfl_xor(m, o));
    float e0 = (j0 <= t) ? __expf(s0 - m) : 0.f;
    float e1 = (j1 <= t) ? __expf(s1 - m) : 0.f;
    float sum = e0 + e1;
    for (int o = 32; o >= 1; o >>= 1) sum += __shfl_xor(sum, o);
    float inv = 1.f / sum;
    p[j0] = e0 * inv;
    p[j1] = e1 * inv;
    __syncthreads();
    float acc = 0.f;
    const float* vcol = QKV + 2 * D + h * DH + lane;
    for (int j = 0; j <= t; ++j) acc += p[j] * vcol[(size_t)j * QKVN];
    AO[(size_t)t * D + h * DH + lane] = f2bf(acc);
}

// ---------------- logits: out[v] = emb[v,:] . xl ----------------
__global__ void logits_kernel(const float* __restrict__ emb, const float* __restrict__ xl,
                              float* __restrict__ out) {
    __shared__ float x[D];
    int tid = threadIdx.x;
    ((float4*)x)[tid] = ((const float4*)xl)[tid];
    __syncthreads();
    int row = blockIdx.x * 4 + (tid >> 6);
    int lane = tid & 63;
    const float4* e4 = (const float4*)(emb + (size_t)row * D);
    const float4* x4 = (const float4*)x;
    float s = 0.f;
    #pragma unroll
    for (int k = lane; k < D / 4; k += 64) {
        float4 ev = e4[k], xv = x4[k];
        s += ev.x * xv.x + ev.y * xv.y + ev.z * xv.z + ev.w * xv.w;
    }
    for (int o = 32; o >= 1; o >>= 1) s += __shfl_xor(s, o);
    if (lane == 0) out[row] = s;
}

extern "C" void kernel_launch(void* const* d_in, const int* in_sizes, int n_in,
                              void* d_out, int out_size, void* d_ws, size_t ws_size,
                              hipStream_t stream) {
    const int*   ids = (const int*)d_in[0];
    const float* emb = (const float*)d_in[1];
    const float* Wq  = (const float*)d_in[2];
    const float* Wk  = (const float*)d_in[3];
    const float* Wv  = (const float*)d_in[4];
    const float* Wo  = (const float*)d_in[5];
    const float* Wg  = (const float*)d_in[6];
    const float* Wu  = (const float*)d_in[7];
    const float* Wd  = (const float*)d_in[8];
    const float* attn_norm = (const float*)d_in[9];
    const float* ffn_norm  = (const float*)d_in[10];
    const float* norm_out  = (const float*)d_in[11];
    float* out = (float*)d_out;

    size_t off = 0;
    auto alloc = [&](size_t bytes) {
        void* p = (char*)d_ws + off;
        off += (bytes + 255) & ~(size_t)255;
        return p;
    };
    float*          X     = (float*)alloc((size_t)T * D * 4);
    float*          QKV   = (float*)alloc((size_t)T * QKVN * 4);
    float*          GU    = (float*)alloc((size_t)T * GUN * 4);
    float*          P1    = (float*)alloc((size_t)NP_O * T * D * 4);  // O-proj partials
    float*          P2    = (float*)alloc((size_t)NP_D * T * D * 4);  // Wd partials
    float*          cosT  = (float*)alloc((size_t)T * 32 * 4);
    float*          sinT  = (float*)alloc((size_t)T * 32 * 4);
    float*          xl    = (float*)alloc((size_t)D * 4);
    unsigned short* Hn_bf = (unsigned short*)alloc((size_t)T * D * 2);
    unsigned short* AO_bf = (unsigned short*)alloc((size_t)T * D * 2);
    unsigned short* Gact  = (unsigned short*)alloc((size_t)T * F * 2);
    (void)ws_size;

    embed_rope_kernel<<<T, 256, 0, stream>>>(ids, emb, X, cosT, sinT);

    for (int l = 0; l < L; ++l) {
        const float* wq = Wq + (size_t)l * D * D;
        const float* wk = Wk + (size_t)l * D * D;
        const float* wv = Wv + (size_t)l * D * D;
        const float* wo = Wo + (size_t)l * D * D;
        const float* wg = Wg + (size_t)l * D * F;
        const float* wu = Wu + (size_t)l * D * F;
        const float* wd = Wd + (size_t)l * F * D;

        // X += prev-layer Wd partials; Hn = rmsnorm(X)*attn_norm (bf16)
        rmsnorm_sum_kernel<true><<<T, 256, 0, stream>>>(
            X, P2, l == 0 ? 0 : NP_D, attn_norm + (size_t)l * D, Hn_bf);
        // QKV[128][3072] = Hn @ {Wq,Wk,Wv}  (full K per block, direct store)
        gemm_wf32_kernel<1024><<<dim3(D / 16, 1, 3), 256, 0, stream>>>(
            Hn_bf, D, wq, wk, wv, D, QKV, QKVN, D, 0);
        attn_rope_kernel<<<dim3(T, H), 64, 0, stream>>>(QKV, cosT, sinT, AO_bf);
        // O-proj -> P1[4] partials (K split 4x256)
        gemm_wf32_kernel<256><<<dim3(D / 16, NP_O, 1), 256, 0, stream>>>(
            AO_bf, D, wo, wo, wo, D, P1, D, 0, (size_t)T * D);
        // X += P1; Hn = rmsnorm(X)*ffn_norm
        rmsnorm_sum_kernel<true><<<T, 256, 0, stream>>>(
            X, P1, NP_O, ffn_norm + (size_t)l * D, Hn_bf);
        // GU[128][5632] = Hn @ {Wg,Wu}
        gemm_wf32_kernel<1024><<<dim3(F / 16, 1, 2), 256, 0, stream>>>(
            Hn_bf, D, wg, wu, wu, F, GU, GUN, F, 0);
        silu_mul_bf16_kernel<<<dim3(F / 256, T), 256, 0, stream>>>(GU, Gact);
        // Wd -> P2[11] partials (K split 11x256)
        gemm_wf32_kernel<256><<<dim3(D / 16, NP_D, 1), 256, 0, stream>>>(
            Gact, F, wd, wd, wd, D, P2, D, 0, (size_t)T * D);
    }

    // final: xl = rmsnorm(X[127] + sum P2[c][127]) * norm_out  (fp32)
    rmsnorm_sum_kernel<false><<<1, 256, 0, stream>>>(
        X + (size_t)(T - 1) * D, P2 + (size_t)(T - 1) * D, NP_D, norm_out, xl);
    logits_kernel<<<V / 4, 256, 0, stream>>>(emb, xl, out);
}

// Round 5
// 815.570 us; speedup vs baseline: 8.4280x; 1.0456x over previous
//
#include <hip/hip_runtime.h>
#include <hip/hip_bf16.h>
#include <math.h>

namespace {
constexpr int V = 32000, D = 1024, L = 8, H = 16, T = 128, F = 2816, DH = 64;
constexpr float EPS = 1e-5f;
constexpr float SCALE = 0.125f; // 1/sqrt(DH)
constexpr int QKVN = 3 * D;     // 3072
constexpr int GUN  = 2 * F;     // 5632
constexpr int NP_Q = 4;         // split-K chunks: QKV (K=1024, CH=256)
constexpr int NP_O = 8;         // O-proj (K=1024, CH=128)
constexpr int NP_G = 4;         // GU (K=1024, CH=256)
constexpr int NP_D = 11;        // Wd (K=2816, CH=256)
}

typedef __attribute__((ext_vector_type(8))) short short8;
typedef __attribute__((ext_vector_type(4))) float f32x4;

__device__ __forceinline__ unsigned short f2bf(float x) {
    union { float f; unsigned u; } v; v.f = x;
    unsigned r = v.u + 0x7FFFu + ((v.u >> 16) & 1u);
    return (unsigned short)(r >> 16);
}

// ---------------- Embedding gather + RoPE tables (fused) ----------------
__global__ void embed_rope_kernel(const int* __restrict__ ids, const float* __restrict__ emb,
                                  float* __restrict__ X,
                                  float* __restrict__ cosT, float* __restrict__ sinT) {
    int t = blockIdx.x, tid = threadIdx.x;
    int id = ids[t];
    ((float4*)(X + (size_t)t * D))[tid] = ((const float4*)(emb + (size_t)id * D))[tid];
    if (tid < 32) {
        float inv = powf(10000.0f, -(2.0f * (float)tid) / (float)DH);
        float ang = (float)t * inv;
        cosT[t * 32 + tid] = cosf(ang);
        sinT[t * 32 + tid] = sinf(ang);
    }
}

// ---------------- RMSNorm + unrolled partial-sum residual update ----------------
// X[t,:] += sum_{c<NP} P[c][t,:]; Y[t,:] = norm(X)*w (bf16 or fp32)
template<int NP, bool BF16OUT>
__launch_bounds__(256)
__global__ void rmsnorm_sum_kernel(float* __restrict__ X, const float* __restrict__ P,
                                   const float* __restrict__ w, void* __restrict__ Y) {
    int t = blockIdx.x, tid = threadIdx.x;
    float4 xv = ((float4*)(X + (size_t)t * D))[tid];
    #pragma unroll
    for (int c = 0; c < NP; ++c) {
        float4 pv = ((const float4*)(P + ((size_t)c * T + t) * D))[tid];
        xv.x += pv.x; xv.y += pv.y; xv.z += pv.z; xv.w += pv.w;
    }
    if (NP) ((float4*)(X + (size_t)t * D))[tid] = xv;
    float s = xv.x * xv.x + xv.y * xv.y + xv.z * xv.z + xv.w * xv.w;
    for (int o = 32; o >= 1; o >>= 1) s += __shfl_xor(s, o);
    __shared__ float red[4];
    if ((tid & 63) == 0) red[tid >> 6] = s;
    __syncthreads();
    float tot = red[0] + red[1] + red[2] + red[3];
    float r = rsqrtf(tot / (float)D + EPS);
    float4 wv = ((const float4*)w)[tid];
    if (BF16OUT) {
        ushort4 y;
        y.x = f2bf(xv.x * r * wv.x); y.y = f2bf(xv.y * r * wv.y);
        y.z = f2bf(xv.z * r * wv.z); y.w = f2bf(xv.w * r * wv.w);
        ((ushort4*)((unsigned short*)Y + (size_t)t * D))[tid] = y;
    } else {
        float4 y;
        y.x = xv.x * r * wv.x; y.y = xv.y * r * wv.y;
        y.z = xv.z * r * wv.z; y.w = xv.w * r * wv.w;
        ((float4*)((float*)Y + (size_t)t * D))[tid] = y;
    }
}

// ---------------- 64-col MFMA GEMM, fp32 [K][N] weights, split-K ----------------
// Block: 64 cols (blockIdx.x), K-chunk CH (blockIdx.y), W0/W1/W2 select (blockIdx.z).
// 4 waves; wave owns 16 cols x all 128 rows (8 m-frags). Weight tile staged
// fp32->bf16 via LDS (256B-coalesced loads), register-prefetched double buffer.
// Partial C stored (plain) to out + blockIdx.y*chunkStride, col += zColOff*z.
template<int CH>
__launch_bounds__(256)
__global__ void gemm64_kernel(const unsigned short* __restrict__ A, int lda,
                              const float* __restrict__ W0, const float* __restrict__ W1,
                              const float* __restrict__ W2, int ldw,
                              float* __restrict__ out, int ldo, int zColOff,
                              size_t chunkStride) {
    constexpr int STAGES = CH / 128;
    constexpr int LSTR = 136;  // ushorts per col (128 + 8 pad)
    __shared__ unsigned short Bst[2][64 * LSTR];
    const float* W = blockIdx.z == 0 ? W0 : (blockIdx.z == 1 ? W1 : W2);
    const int tid = threadIdx.x;
    const int wave = tid >> 6, lane = tid & 63;
    const int n0 = blockIdx.x * 64;
    const int k0 = blockIdx.y * CH;

    // staging mapping: thread -> (col sc, octet group so); a wave's load of one
    // k-row covers 64 consecutive floats = 256 B contiguous.
    const int sc = tid & 63;
    const int so = tid >> 6;
    const float* wCol = W + (size_t)k0 * ldw + n0 + sc;
    unsigned short* wp = &Bst[0][sc * LSTR];

    // compute mapping
    const int lrow = lane & 15;
    const int lqo = lane >> 4;
    const unsigned short* aB = A + (size_t)lrow * lda + k0 + lqo * 8;
    const unsigned short* bRd = &Bst[0][(wave * 16 + lrow) * LSTR + lqo * 8];

    f32x4 acc[8] = {};
    float pre[32];

    auto ldst = [&](int s) {
        #pragma unroll
        for (int p = 0; p < 4; ++p) {
            const float* src = wCol + (size_t)(s * 128 + (so * 4 + p) * 8) * ldw;
            #pragma unroll
            for (int j = 0; j < 8; ++j) pre[p * 8 + j] = src[(size_t)j * ldw];
        }
    };
    auto wrst = [&](int buf) {
        #pragma unroll
        for (int p = 0; p < 4; ++p) {
            short8 bv;
            #pragma unroll
            for (int j = 0; j < 8; ++j) bv[j] = (short)f2bf(pre[p * 8 + j]);
            *(short8*)(wp + buf * (64 * LSTR) + (so * 4 + p) * 8) = bv;
        }
    };

    ldst(0);
    wrst(0);
    __syncthreads();

    #pragma unroll
    for (int s = 0; s < STAGES; ++s) {
        if (s + 1 < STAGES) ldst(s + 1);  // issue next-stage loads early
        const unsigned short* rd = bRd + (s & 1) * (64 * LSTR);
        #pragma unroll
        for (int ks = 0; ks < 4; ++ks) {
            short8 b = *(const short8*)(rd + ks * 32);  // octet (ks*4+lqo)
            #pragma unroll
            for (int mf = 0; mf < 8; ++mf) {
                short8 a = *(const short8*)(aB + (size_t)(mf * 16) * lda + s * 128 + ks * 32);
                acc[mf] = __builtin_amdgcn_mfma_f32_16x16x32_bf16(a, b, acc[mf], 0, 0, 0);
            }
        }
        if (s + 1 < STAGES) {
            __syncthreads();
            wrst((s + 1) & 1);
            __syncthreads();
        }
    }

    const int col = zColOff * blockIdx.z + n0 + wave * 16 + lrow;
    float* op = out + blockIdx.y * chunkStride;
    #pragma unroll
    for (int mf = 0; mf < 8; ++mf) {
        int r0 = mf * 16 + lqo * 4;
        #pragma unroll
        for (int r = 0; r < 4; ++r)
            op[(size_t)(r0 + r) * ldo + col] = acc[mf][r];
    }
}

// ---------------- QKV partial reduce + RoPE -> compact Q,K,V [T][D] fp32 ----------------
__launch_bounds__(256)
__global__ void rope_reduce_kernel(const float* __restrict__ P,
                                   const float* __restrict__ cosT, const float* __restrict__ sinT,
                                   float* __restrict__ Qr, float* __restrict__ Kr,
                                   float* __restrict__ Vr) {
    int t = blockIdx.x, tid = threadIdx.x;
    int d0 = tid * 4;
    float4 q = {0.f, 0.f, 0.f, 0.f}, k = q, v = q;
    #pragma unroll
    for (int c = 0; c < NP_Q; ++c) {
        const float* base = P + ((size_t)c * T + t) * QKVN;
        float4 a = ((const float4*)base)[tid];
        float4 b = ((const float4*)(base + D))[tid];
        float4 w = ((const float4*)(base + 2 * D))[tid];
        q.x += a.x; q.y += a.y; q.z += a.z; q.w += a.w;
        k.x += b.x; k.y += b.y; k.z += b.z; k.w += b.w;
        v.x += w.x; v.y += w.y; v.z += w.z; v.w += w.w;
    }
    float4 c4 = *(const float4*)(cosT + t * 32 + (d0 & 31));
    float4 s4 = *(const float4*)(sinT + t * 32 + (d0 & 31));
    float sgn = (d0 & 32) ? 1.f : -1.f;
    float4 qp, kp;
    qp.x = __shfl_xor(q.x, 8); qp.y = __shfl_xor(q.y, 8);
    qp.z = __shfl_xor(q.z, 8); qp.w = __shfl_xor(q.w, 8);
    kp.x = __shfl_xor(k.x, 8); kp.y = __shfl_xor(k.y, 8);
    kp.z = __shfl_xor(k.z, 8); kp.w = __shfl_xor(k.w, 8);
    float4 qo, ko;
    qo.x = q.x * c4.x + sgn * qp.x * s4.x; qo.y = q.y * c4.y + sgn * qp.y * s4.y;
    qo.z = q.z * c4.z + sgn * qp.z * s4.z; qo.w = q.w * c4.w + sgn * qp.w * s4.w;
    ko.x = k.x * c4.x + sgn * kp.x * s4.x; ko.y = k.y * c4.y + sgn * kp.y * s4.y;
    ko.z = k.z * c4.z + sgn * kp.z * s4.z; ko.w = k.w * c4.w + sgn * kp.w * s4.w;
    ((float4*)(Qr + (size_t)t * D))[tid] = qo;
    ((float4*)(Kr + (size_t)t * D))[tid] = ko;
    ((float4*)(Vr + (size_t)t * D))[tid] = v;
}

// ---------------- Causal attention on compact Q,K,V; bf16 out ----------------
__global__ void attn_kernel(const float* __restrict__ Q, const float* __restrict__ Kc,
                            const float* __restrict__ Vc, unsigned short* __restrict__ AO) {
    int t = blockIdx.x, h = blockIdx.y, lane = threadIdx.x;
    __shared__ float q[DH];
    __shared__ float p[T];
    q[lane] = Q[(size_t)t * D + h * DH + lane];
    __syncthreads();
    int j0 = lane, j1 = lane + 64;
    float s0 = -1e30f, s1 = -1e30f;
    if (j0 <= t) {
        const float* kr = Kc + (size_t)j0 * D + h * DH;
        float s = 0.f;
        #pragma unroll
        for (int d = 0; d < DH; ++d) s += q[d] * kr[d];
        s0 = s * SCALE;
    }
    if (j1 <= t) {
        const float* kr = Kc + (size_t)j1 * D + h * DH;
        float s = 0.f;
        #pragma unroll
        for (int d = 0; d < DH; ++d) s += q[d] * kr[d];
        s1 = s * SCALE;
    }
    float m = fmaxf(s0, s1);
    for (int o = 32; o >= 1; o >>= 1) m = fmaxf(m, __shfl_xor(m, o));
    float e0 = (j0 <= t) ? __expf(s0 - m) : 0.f;
    float e1 = (j1 <= t) ? __expf(s1 - m) : 0.f;
    float sum = e0 + e1;
    for (int o = 32; o >= 1; o >>= 1) sum += __shfl_xor(sum, o);
    float inv = 1.f / sum;
    p[j0] = e0 * inv;
    p[j1] = e1 * inv;
    __syncthreads();
    float acc = 0.f;
    const float* vcol = Vc + h * DH + lane;
    for (int j = 0; j <= t; ++j) acc += p[j] * vcol[(size_t)j * D];
    AO[(size_t)t * D + h * DH + lane] = f2bf(acc);
}

// ---------------- GU partial reduce + silu(g)*u -> Gact bf16 [T][F] ----------------
__launch_bounds__(256)
__global__ void silu_reduce_kernel(const float* __restrict__ P,
                                   unsigned short* __restrict__ Gact) {
    int t = blockIdx.y;
    int f = blockIdx.x * 256 + threadIdx.x;
    float g = 0.f, u = 0.f;
    #pragma unroll
    for (int c = 0; c < NP_G; ++c) {
        const float* base = P + ((size_t)c * T + t) * GUN;
        g += base[f];
        u += base[F + f];
    }
    Gact[(size_t)t * F + f] = f2bf(g / (1.f + __expf(-g)) * u);
}

// ---------------- logits: out[v] = emb[v,:] . xl ----------------
__global__ void logits_kernel(const float* __restrict__ emb, const float* __restrict__ xl,
                              float* __restrict__ out) {
    __shared__ float x[D];
    int tid = threadIdx.x;
    ((float4*)x)[tid] = ((const float4*)xl)[tid];
    __syncthreads();
    int row = blockIdx.x * 4 + (tid >> 6);
    int lane = tid & 63;
    const float4* e4 = (const float4*)(emb + (size_t)row * D);
    const float4* x4 = (const float4*)x;
    float s = 0.f;
    #pragma unroll
    for (int k = lane; k < D / 4; k += 64) {
        float4 ev = e4[k], xv = x4[k];
        s += ev.x * xv.x + ev.y * xv.y + ev.z * xv.z + ev.w * xv.w;
    }
    for (int o = 32; o >= 1; o >>= 1) s += __shfl_xor(s, o);
    if (lane == 0) out[row] = s;
}

extern "C" void kernel_launch(void* const* d_in, const int* in_sizes, int n_in,
                              void* d_out, int out_size, void* d_ws, size_t ws_size,
                              hipStream_t stream) {
    const int*   ids = (const int*)d_in[0];
    const float* emb = (const float*)d_in[1];
    const float* Wq  = (const float*)d_in[2];
    const float* Wk  = (const float*)d_in[3];
    const float* Wv  = (const float*)d_in[4];
    const float* Wo  = (const float*)d_in[5];
    const float* Wg  = (const float*)d_in[6];
    const float* Wu  = (const float*)d_in[7];
    const float* Wd  = (const float*)d_in[8];
    const float* attn_norm = (const float*)d_in[9];
    const float* ffn_norm  = (const float*)d_in[10];
    const float* norm_out  = (const float*)d_in[11];
    float* out = (float*)d_out;

    size_t off = 0;
    auto alloc = [&](size_t bytes) {
        void* p = (char*)d_ws + off;
        off += (bytes + 255) & ~(size_t)255;
        return p;
    };
    float*          X     = (float*)alloc((size_t)T * D * 4);
    float*          P0    = (float*)alloc((size_t)NP_Q * T * QKVN * 4);  // QKV partials
    float*          P1    = (float*)alloc((size_t)NP_O * T * D * 4);     // O-proj partials
    float*          P2    = (float*)alloc((size_t)NP_D * T * D * 4);     // Wd partials
    float*          P3    = (float*)alloc((size_t)NP_G * T * GUN * 4);   // GU partials
    float*          Qr    = (float*)alloc((size_t)T * D * 4);
    float*          Kr    = (float*)alloc((size_t)T * D * 4);
    float*          Vr    = (float*)alloc((size_t)T * D * 4);
    float*          cosT  = (float*)alloc((size_t)T * 32 * 4);
    float*          sinT  = (float*)alloc((size_t)T * 32 * 4);
    float*          xl    = (float*)alloc((size_t)D * 4);
    unsigned short* Hn_bf = (unsigned short*)alloc((size_t)T * D * 2);
    unsigned short* AO_bf = (unsigned short*)alloc((size_t)T * D * 2);
    unsigned short* Gact  = (unsigned short*)alloc((size_t)T * F * 2);
    (void)ws_size;

    embed_rope_kernel<<<T, 256, 0, stream>>>(ids, emb, X, cosT, sinT);

    for (int l = 0; l < L; ++l) {
        const float* wq = Wq + (size_t)l * D * D;
        const float* wk = Wk + (size_t)l * D * D;
        const float* wv = Wv + (size_t)l * D * D;
        const float* wo = Wo + (size_t)l * D * D;
        const float* wg = Wg + (size_t)l * D * F;
        const float* wu = Wu + (size_t)l * D * F;
        const float* wd = Wd + (size_t)l * F * D;

        // X += prev-layer Wd partials; Hn = rmsnorm(X)*attn_norm (bf16)
        if (l == 0)
            rmsnorm_sum_kernel<0, true><<<T, 256, 0, stream>>>(
                X, P2, attn_norm + (size_t)l * D, Hn_bf);
        else
            rmsnorm_sum_kernel<NP_D, true><<<T, 256, 0, stream>>>(
                X, P2, attn_norm + (size_t)l * D, Hn_bf);
        // QKV partials: K=1024 split 4x256, z in {q,k,v} -> 192 blocks
        gemm64_kernel<256><<<dim3(D / 64, NP_Q, 3), 256, 0, stream>>>(
            Hn_bf, D, wq, wk, wv, D, P0, QKVN, D, (size_t)T * QKVN);
        rope_reduce_kernel<<<T, 256, 0, stream>>>(P0, cosT, sinT, Qr, Kr, Vr);
        attn_kernel<<<dim3(T, H), 64, 0, stream>>>(Qr, Kr, Vr, AO_bf);
        // O-proj partials: K=1024 split 8x128 -> 128 blocks
        gemm64_kernel<128><<<dim3(D / 64, NP_O, 1), 256, 0, stream>>>(
            AO_bf, D, wo, wo, wo, D, P1, D, 0, (size_t)T * D);
        rmsnorm_sum_kernel<NP_O, true><<<T, 256, 0, stream>>>(
            X, P1, ffn_norm + (size_t)l * D, Hn_bf);
        // GU partials: K=1024 split 4x256, z in {g,u} -> 352 blocks
        gemm64_kernel<256><<<dim3(F / 64, NP_G, 2), 256, 0, stream>>>(
            Hn_bf, D, wg, wu, wu, F, P3, GUN, F, (size_t)T * GUN);
        silu_reduce_kernel<<<dim3(F / 256, T), 256, 0, stream>>>(P3, Gact);
        // Wd partials: K=2816 split 11x256 -> 176 blocks
        gemm64_kernel<256><<<dim3(D / 64, NP_D, 1), 256, 0, stream>>>(
            Gact, F, wd, wd, wd, D, P2, D, 0, (size_t)T * D);
    }

    // final: xl = rmsnorm(X[127] + sum P2[c][127]) * norm_out (fp32)
    rmsnorm_sum_kernel<NP_D, false><<<1, 256, 0, stream>>>(
        X + (size_t)(T - 1) * D, P2 + (size_t)(T - 1) * D, norm_out, xl);
    logits_kernel<<<V / 4, 256, 0, stream>>>(emb, xl, out);
}